// Round 2
// baseline (465.343 us; speedup 1.0000x reference)
//
#include <hip/hip_runtime.h>

typedef unsigned short u16;
typedef unsigned int u32;
typedef __attribute__((ext_vector_type(8))) __bf16 bf16x8;
typedef __attribute__((ext_vector_type(4))) float f32x4;
typedef __attribute__((ext_vector_type(8))) u16 u16x8;
typedef __attribute__((ext_vector_type(4))) u16 u16x4;

typedef const __attribute__((address_space(1))) u32* gas_p;
typedef __attribute__((address_space(3))) u32* las_p;

__device__ __forceinline__ void gload16(const void* g, void* l) {
  __builtin_amdgcn_global_load_lds((gas_p)g, (las_p)l, 16, 0, 0);
}

__device__ __forceinline__ u16 f2bf(float f) {
  u32 u = __builtin_bit_cast(u32, f);
  u32 r = (u + 0x7fffu + ((u >> 16) & 1u)) >> 16;
  return (u16)r;
}

// ---------------- fp32 -> bf16 conversion (float4 vectorized) ----------------
__global__ __launch_bounds__(256) void conv_bf16(const float* __restrict__ in,
                                                 u16* __restrict__ out, int n) {
  int i = (blockIdx.x * 256 + threadIdx.x) * 4;
  if (i < n) {
    const float4 v = *(const float4*)(in + i);
    u16x4 o = {f2bf(v.x), f2bf(v.y), f2bf(v.z), f2bf(v.w)};
    *(u16x4*)(out + i) = o;
  }
}

// ------------- transpose + convert: in [R=4096][C=256] f32 -> out [C][R] bf16 -------------
__global__ __launch_bounds__(256) void transpose_conv(const float* __restrict__ in,
                                                      u16* __restrict__ out) {
  const int R = 4096, Cc = 256;
  __shared__ float t[32][33];
  const int r0 = blockIdx.x * 32, c0 = blockIdx.y * 32;
  const int lx = threadIdx.x & 31, ly = threadIdx.x >> 5;  // ly: 0..7
#pragma unroll
  for (int i = 0; i < 4; ++i)
    t[ly + i * 8][lx] = in[(size_t)(r0 + ly + i * 8) * Cc + c0 + lx];
  __syncthreads();
#pragma unroll
  for (int i = 0; i < 4; ++i)
    out[(size_t)(c0 + ly + i * 8) * R + r0 + lx] = f2bf(t[lx][ly + i * 8]);
}

// ---------------- bf16 GEMM: C[M][N] = A[M][K] * B[N][K]^T ----------------
// 128x128 tile, BK=32, 4 waves (2x2), 4x4 16x16x32 frags per wave.
// global_load_lds with pre-swizzled source: LDS[row][b ^ ((row&3)<<4)] = G[row][b]
// OUTM: 0 = f32 plain, 1 = bf16 plain, 2 = bf16 transposed per-256-row-batch
//       (C rows are (b*256+kp); writes Ct[b][n][kp], kp-stride-1 via u16x4)
template <int OUTM>
__global__ __launch_bounds__(256) void gemm_bt(const u16* __restrict__ A,
                                               const u16* __restrict__ B,
                                               void* __restrict__ C, int M, int N,
                                               int K) {
  __shared__ u16 lds[2][128 * 32];
  const int tid = threadIdx.x, l = tid & 63, w = tid >> 6;
  const int m0 = blockIdx.x * 128, n0 = blockIdx.y * 128;
  const int wr = w >> 1, wc = w & 1;
  f32x4 acc[4][4] = {};
  for (int k0 = 0; k0 < K; k0 += 32) {
#pragma unroll
    for (int i = 0; i < 2; ++i) {
      const int c = i * 256 + tid;
      const int row = c >> 2;
      const int scb = ((c & 3) << 4) ^ ((row & 3) << 4);
      gload16((const char*)A + ((size_t)(m0 + row) * K + k0) * 2 + scb,
              (char*)&lds[0][0] + (size_t)(i * 256 + w * 64) * 16);
      gload16((const char*)B + ((size_t)(n0 + row) * K + k0) * 2 + scb,
              (char*)&lds[1][0] + (size_t)(i * 256 + w * 64) * 16);
    }
    __syncthreads();
    bf16x8 af[4], bf[4];
#pragma unroll
    for (int f = 0; f < 4; ++f) {
      const int ra = wr * 64 + f * 16 + (l & 15);
      af[f] = *(const bf16x8*)((const char*)&lds[0][0] + ra * 64 +
                               (((l >> 4) * 16) ^ ((ra & 3) << 4)));
      const int rb = wc * 64 + f * 16 + (l & 15);
      bf[f] = *(const bf16x8*)((const char*)&lds[1][0] + rb * 64 +
                               (((l >> 4) * 16) ^ ((rb & 3) << 4)));
    }
#pragma unroll
    for (int mf = 0; mf < 4; ++mf)
#pragma unroll
      for (int nf = 0; nf < 4; ++nf)
        acc[mf][nf] = __builtin_amdgcn_mfma_f32_16x16x32_bf16(af[mf], bf[nf],
                                                              acc[mf][nf], 0, 0, 0);
    __syncthreads();
  }
#pragma unroll
  for (int mf = 0; mf < 4; ++mf) {
    const int rbase = m0 + wr * 64 + mf * 16 + ((l >> 4) << 2);
#pragma unroll
    for (int nf = 0; nf < 4; ++nf) {
      const int cc = n0 + wc * 64 + nf * 16 + (l & 15);
      if (OUTM == 2) {
        const int b = rbase >> 8, kp = rbase & 255;
        u16x4 o = {f2bf(acc[mf][nf][0]), f2bf(acc[mf][nf][1]), f2bf(acc[mf][nf][2]),
                   f2bf(acc[mf][nf][3])};
        *(u16x4*)((u16*)C + ((size_t)b * 1024 + cc) * 256 + kp) = o;
      } else {
#pragma unroll
        for (int j = 0; j < 4; ++j) {
          if (OUTM == 1)
            ((u16*)C)[(size_t)(rbase + j) * N + cc] = f2bf(acc[mf][nf][j]);
          else
            ((float*)C)[(size_t)(rbase + j) * N + cc] = acc[mf][nf][j];
        }
      }
    }
  }
}

// ------- Linformer projection on HS: out[b][kp][j] = sum_s Pt[kp][s] * hs[b][s][j] -------
// z = b*2 + wv (wv: 0 -> E path -> hsE, 1 -> F path -> hsF)
// 64x64 tile, BK=32, 4 waves (2x2), 2x2 frags each. B (hs) staged transposed via scatter.
__global__ __launch_bounds__(256) void proj_gemm(const u16* __restrict__ Et,
                                                 const u16* __restrict__ Ft,
                                                 const u16* __restrict__ hs,
                                                 u16* __restrict__ hsE,
                                                 u16* __restrict__ hsF) {
  const int tid = threadIdx.x, l = tid & 63, w = tid >> 6;
  const int wv = blockIdx.z & 1, b = blockIdx.z >> 1;
  const int m0 = blockIdx.x * 64, n0 = blockIdx.y * 64;
  const u16* Ap = wv ? Ft : Et;                 // [256][4096]
  const u16* Bp = hs + (size_t)b * 4096 * 1024; // [s][j], ld 1024
  __shared__ u16 ldsA[64 * 32], ldsB[64 * 32];  // ldsB stored transposed: [j][s]
  const int wr = w >> 1, wc = w & 1;
  f32x4 acc[2][2] = {};
  for (int k0 = 0; k0 < 4096; k0 += 32) {
    {  // A stage: 256 chunks of 16B, pre-swizzled source
      const int row = tid >> 2;
      const int scb = ((tid & 3) << 4) ^ ((row & 3) << 4);
      gload16((const char*)Ap + ((size_t)(m0 + row) * 4096 + k0) * 2 + scb,
              (char*)ldsA + (size_t)w * 64 * 16);
    }
    {  // B stage with transpose: read [s][j] 16B, scatter to ldsB[j][s] (swizzled)
      const int s = tid >> 3, nb = (tid & 7) * 8;
      const u16x8 v = *(const u16x8*)(Bp + (size_t)(k0 + s) * 1024 + n0 + nb);
#pragma unroll
      for (int j = 0; j < 8; ++j) {
        const int nrow = nb + j;
        *(u16*)((char*)ldsB + nrow * 64 + ((s * 2) ^ ((nrow & 3) << 4))) = v[j];
      }
    }
    __syncthreads();
    bf16x8 af[2], bf[2];
#pragma unroll
    for (int f = 0; f < 2; ++f) {
      const int ra = wr * 32 + f * 16 + (l & 15);
      af[f] = *(const bf16x8*)((const char*)ldsA + ra * 64 +
                               (((l >> 4) * 16) ^ ((ra & 3) << 4)));
      const int rb = wc * 32 + f * 16 + (l & 15);
      bf[f] = *(const bf16x8*)((const char*)ldsB + rb * 64 +
                               (((l >> 4) * 16) ^ ((rb & 3) << 4)));
    }
#pragma unroll
    for (int mf = 0; mf < 2; ++mf)
#pragma unroll
      for (int nf = 0; nf < 2; ++nf)
        acc[mf][nf] = __builtin_amdgcn_mfma_f32_16x16x32_bf16(af[mf], bf[nf],
                                                              acc[mf][nf], 0, 0, 0);
    __syncthreads();
  }
  u16* outp = wv ? hsF : hsE;
#pragma unroll
  for (int mf = 0; mf < 2; ++mf) {
    const int kp0 = m0 + wr * 32 + mf * 16 + ((l >> 4) << 2);
#pragma unroll
    for (int nf = 0; nf < 2; ++nf) {
      const int n = n0 + wc * 32 + nf * 16 + (l & 15);
#pragma unroll
      for (int j = 0; j < 4; ++j)
        outp[((size_t)b * 256 + kp0 + j) * 1024 + n] = f2bf(acc[mf][nf][j]);
    }
  }
}

// ---------------- fused attention ----------------
// block: (qtile 64 rows, head, batch); 256 threads = 4 waves x 16 q-rows.
// LDS 64KB: [0,32KB) = K' [256][64] (XOR-swizzled, later overlaid by P),
//           [32KB,64KB) = V'^T [64][256] (swizzled)
__global__ __launch_bounds__(256) void attn_kernel(const u16* __restrict__ qmat,
                                                   const u16* __restrict__ kproj,
                                                   const u16* __restrict__ vprojT,
                                                   u16* __restrict__ aout) {
  __shared__ u16 smem[32768];
  const int tid = threadIdx.x, l = tid & 63, w = tid >> 6;
  const int qt = blockIdx.x, h = blockIdx.y, b = blockIdx.z;
  const int qbase = qt * 64;

  // ---- stage K' [256 rows x 128B], swizzle byte ^= (row&7)<<4 ----
#pragma unroll
  for (int i = 0; i < 8; ++i) {
    const int c = i * 256 + tid;
    const int row = c >> 3;
    const int scb = ((c & 7) << 4) ^ ((row & 7) << 4);
    gload16((const char*)kproj + (((size_t)(b * 256 + row)) * 1024 + h * 64) * 2 + scb,
            (char*)smem + (size_t)(i * 256 + w * 64) * 16);
  }
  // ---- stage V'^T [64 rows x 512B], swizzle byte ^= (d&31)<<4 ----
#pragma unroll
  for (int i = 0; i < 8; ++i) {
    const int c = i * 256 + tid;
    const int d = c >> 5;
    const int scb = ((c & 31) << 4) ^ ((d & 31) << 4);
    gload16((const char*)vprojT + ((size_t)(b * 1024 + h * 64 + d)) * 256 * 2 + scb,
            (char*)smem + 32768 + (size_t)(i * 256 + w * 64) * 16);
  }
  __syncthreads();

  // ---- Q fragments straight from global (16B per lane) ----
  const u16* qrow =
      qmat + ((size_t)(b * 4096 + qbase + w * 16 + (l & 15))) * 1024 + h * 64;
  bf16x8 qa[2];
#pragma unroll
  for (int kf = 0; kf < 2; ++kf)
    qa[kf] = *(const bf16x8*)(qrow + kf * 32 + (l >> 4) * 8);

  // ---- S = Q K'^T: 16 n-frags x 2 k-frags ----
  f32x4 s[16] = {};
#pragma unroll
  for (int nf = 0; nf < 16; ++nf) {
    const int kr = nf * 16 + (l & 15);
#pragma unroll
    for (int kf = 0; kf < 2; ++kf) {
      const bf16x8 kb = *(const bf16x8*)((const char*)smem + kr * 128 +
                                         ((kf * 64 + (l >> 4) * 16) ^ ((kr & 7) << 4)));
      s[nf] = __builtin_amdgcn_mfma_f32_16x16x32_bf16(qa[kf], kb, s[nf], 0, 0, 0);
    }
  }

  // ---- wave-parallel softmax over kp=256 (scale 1/8 inside exp), in place ----
  float mx[4] = {-1e30f, -1e30f, -1e30f, -1e30f}, sum[4] = {0.f, 0.f, 0.f, 0.f};
#pragma unroll
  for (int j = 0; j < 4; ++j) {
#pragma unroll
    for (int nf = 0; nf < 16; ++nf) mx[j] = fmaxf(mx[j], s[nf][j]);
#pragma unroll
    for (int m = 1; m < 16; m <<= 1) mx[j] = fmaxf(mx[j], __shfl_xor(mx[j], m, 64));
  }
#pragma unroll
  for (int nf = 0; nf < 16; ++nf)
#pragma unroll
    for (int j = 0; j < 4; ++j) {
      const float e = __expf((s[nf][j] - mx[j]) * 0.125f);
      s[nf][j] = e;
      sum[j] += e;
    }
#pragma unroll
  for (int j = 0; j < 4; ++j) {
#pragma unroll
    for (int m = 1; m < 16; m <<= 1) sum[j] += __shfl_xor(sum[j], m, 64);
    sum[j] = 1.0f / sum[j];
  }

  __syncthreads();  // all waves done reading K' before P overlays it

  // ---- write P (bf16) into per-wave region of the K' union, swizzled ----
  u16* Pw = smem + w * 4096;  // 16 rows x 512B
#pragma unroll
  for (int nf = 0; nf < 16; ++nf) {
    const int col = nf * 16 + (l & 15);
#pragma unroll
    for (int j = 0; j < 4; ++j) {
      const int row = (l >> 4) * 4 + j;
      *(u16*)((char*)Pw + row * 512 + ((col * 2) ^ (row << 4))) =
          f2bf(s[nf][j] * sum[j]);
    }
  }
  __syncthreads();

  // ---- O^T[d][q] = V'^T * P^T : 4 d-frags x 8 k-steps ----
  f32x4 o[4] = {};
#pragma unroll
  for (int kf = 0; kf < 8; ++kf) {
    const int q = l & 15;
    const bf16x8 pb = *(const bf16x8*)((const char*)Pw + q * 512 +
                                       ((kf * 64 + (l >> 4) * 16) ^ (q << 4)));
#pragma unroll
    for (int mf = 0; mf < 4; ++mf) {
      const int d = mf * 16 + (l & 15);
      const bf16x8 va = *(const bf16x8*)((const char*)smem + 32768 + d * 512 +
                                         ((kf * 64 + (l >> 4) * 16) ^ ((d & 31) << 4)));
      o[mf] = __builtin_amdgcn_mfma_f32_16x16x32_bf16(va, pb, o[mf], 0, 0, 0);
    }
  }

  // ---- write attn_out [b][s][h*64+d] (8B stores: 4 consecutive d) ----
#pragma unroll
  for (int mf = 0; mf < 4; ++mf) {
    const int d0 = mf * 16 + ((l >> 4) << 2);
    const int srow = b * 4096 + qbase + w * 16 + (l & 15);
    u16x4 ov = {f2bf(o[mf][0]), f2bf(o[mf][1]), f2bf(o[mf][2]), f2bf(o[mf][3])};
    *(u16x4*)(aout + (size_t)srow * 1024 + h * 64 + d0) = ov;
  }
}

// ---------------- host launch ----------------
extern "C" void kernel_launch(void* const* d_in, const int* in_sizes, int n_in,
                              void* d_out, int out_size, void* d_ws, size_t ws_size,
                              hipStream_t stream) {
  const float* hs = (const float*)d_in[0];
  const float* Wq = (const float*)d_in[1];
  const float* Wk = (const float*)d_in[2];
  const float* Wv = (const float*)d_in[3];
  const float* Wo = (const float*)d_in[4];
  const float* E = (const float*)d_in[5];
  const float* F = (const float*)d_in[6];

  char* ws = (char*)d_ws;
  u16* hs_bf = (u16*)(ws + 0);              // 32 MiB  [16384][1024]
  u16* qout = (u16*)(ws + 33554432);        // 32 MiB  [16384][1024]
  u16* aout = (u16*)(ws + 67108864);        // 32 MiB  [16384][1024]
  u16* Wq_bf = (u16*)(ws + 100663296);      // 2 MiB
  u16* Wk_bf = (u16*)(ws + 102760448);      // 2 MiB
  u16* Wv_bf = (u16*)(ws + 104857600);      // 2 MiB
  u16* Wo_bf = (u16*)(ws + 106954752);      // 2 MiB
  u16* Et_bf = (u16*)(ws + 109051904);      // 2 MiB   [256][4096]
  u16* Ft_bf = (u16*)(ws + 111149056);      // 2 MiB   [256][4096]
  u16* hsE = (u16*)(ws + 113246208);        // 2 MiB   [4][256][1024]
  u16* hsF = (u16*)(ws + 115343360);        // 2 MiB   [4][256][1024]
  u16* kproj = (u16*)(ws + 117440512);      // 2 MiB   [4][256][1024]
  u16* vprojT = (u16*)(ws + 119537664);     // 2 MiB   [4][1024][256]

  conv_bf16<<<16384, 256, 0, stream>>>(hs, hs_bf, 16777216);
  conv_bf16<<<1024, 256, 0, stream>>>(Wq, Wq_bf, 1048576);
  conv_bf16<<<1024, 256, 0, stream>>>(Wk, Wk_bf, 1048576);
  conv_bf16<<<1024, 256, 0, stream>>>(Wv, Wv_bf, 1048576);
  conv_bf16<<<1024, 256, 0, stream>>>(Wo, Wo_bf, 1048576);
  transpose_conv<<<dim3(128, 8), 256, 0, stream>>>(E, Et_bf);
  transpose_conv<<<dim3(128, 8), 256, 0, stream>>>(F, Ft_bf);

  // q = hs @ Wq^T  [16384][1024]
  gemm_bt<1><<<dim3(128, 8), 256, 0, stream>>>(hs_bf, Wq_bf, qout, 16384, 1024, 1024);
  // hsE[b] = E^T @ hs[b], hsF[b] = F^T @ hs[b]   [4][256][1024]
  proj_gemm<<<dim3(4, 16, 8), 256, 0, stream>>>(Et_bf, Ft_bf, hs_bf, hsE, hsF);
  // k' = hsE @ Wk^T -> kproj [4][256][1024] ;  v'^T -> vprojT [4][1024][256]
  gemm_bt<1><<<dim3(8, 8), 256, 0, stream>>>(hsE, Wk_bf, kproj, 1024, 1024, 1024);
  gemm_bt<2><<<dim3(8, 8), 256, 0, stream>>>(hsF, Wv_bf, vprojT, 1024, 1024, 1024);

  attn_kernel<<<dim3(64, 16, 4), 256, 0, stream>>>(qout, kproj, vprojT, aout);
  // out = attn_out @ Wo^T  (fp32 epilogue straight to d_out)
  gemm_bt<0><<<dim3(128, 8), 256, 0, stream>>>(aout, Wo_bf, d_out, 16384, 1024, 1024);
}

// Round 7
// 404.082 us; speedup vs baseline: 1.1516x; 1.1516x over previous
//
#include <hip/hip_runtime.h>

typedef unsigned short u16;
typedef unsigned int u32;
typedef __attribute__((ext_vector_type(8))) __bf16 bf16x8;
typedef __attribute__((ext_vector_type(4))) float f32x4;
typedef __attribute__((ext_vector_type(8))) u16 u16x8;
typedef __attribute__((ext_vector_type(4))) u16 u16x4;

typedef const __attribute__((address_space(1))) u32* gas_p;
typedef __attribute__((address_space(3))) u32* las_p;

__device__ __forceinline__ void gload16(const void* g, void* l) {
  __builtin_amdgcn_global_load_lds((gas_p)g, (las_p)l, 16, 0, 0);
}

__device__ __forceinline__ u16 f2bf(float f) {
  u32 u = __builtin_bit_cast(u32, f);
  u32 r = (u + 0x7fffu + ((u >> 16) & 1u)) >> 16;
  return (u16)r;
}

// ---- fused hs conversion: hs [16384][1024] f32 -> hs_bf (same layout) + hsT2 [4][1024][4096] ----
__global__ __launch_bounds__(256) void conv_hs(const float* __restrict__ in,
                                               u16* __restrict__ out_row,
                                               u16* __restrict__ out_t) {
  __shared__ u16 t[32][34];
  const int r0 = blockIdx.x * 32, c0 = blockIdx.y * 32;
  const int lx = threadIdx.x & 31, ly = threadIdx.x >> 5;  // ly: 0..7
#pragma unroll
  for (int i = 0; i < 4; ++i) {
    const int r = r0 + ly + i * 8;
    const u16 v = f2bf(in[(size_t)r * 1024 + c0 + lx]);
    out_row[(size_t)r * 1024 + c0 + lx] = v;
    t[ly + i * 8][lx] = v;
  }
  __syncthreads();
  const int b = r0 >> 12, s0 = r0 & 4095;
#pragma unroll
  for (int i = 0; i < 4; ++i)
    out_t[((size_t)b * 1024 + c0 + ly + i * 8) * 4096 + s0 + lx] = t[lx][ly + i * 8];
}

// ---- 4 weight matrices fp32 -> bf16, one launch ----
__global__ __launch_bounds__(256) void conv_w4(const float* __restrict__ a,
                                               const float* __restrict__ b,
                                               const float* __restrict__ c,
                                               const float* __restrict__ d,
                                               u16* __restrict__ out) {
  const float* src = blockIdx.y == 0 ? a : blockIdx.y == 1 ? b : blockIdx.y == 2 ? c : d;
  const int i = (blockIdx.x * 256 + threadIdx.x) * 4;
  const float4 v = *(const float4*)(src + i);
  u16x4 o = {f2bf(v.x), f2bf(v.y), f2bf(v.z), f2bf(v.w)};
  *(u16x4*)(out + (size_t)blockIdx.y * 1048576 + i) = o;
}

// ---- transpose + convert: in [4096][256] f32 -> out [256][4096] bf16 ----
__global__ __launch_bounds__(256) void transpose_conv(const float* __restrict__ in,
                                                      u16* __restrict__ out) {
  const int R = 4096, Cc = 256;
  __shared__ float t[32][33];
  const int r0 = blockIdx.x * 32, c0 = blockIdx.y * 32;
  const int lx = threadIdx.x & 31, ly = threadIdx.x >> 5;
#pragma unroll
  for (int i = 0; i < 4; ++i)
    t[ly + i * 8][lx] = in[(size_t)(r0 + ly + i * 8) * Cc + c0 + lx];
  __syncthreads();
#pragma unroll
  for (int i = 0; i < 4; ++i)
    out[(size_t)(c0 + ly + i * 8) * R + r0 + lx] = f2bf(t[lx][ly + i * 8]);
}

// ---------------- bf16 GEMM: C[M][N] = A[M][K] * B[N][K]^T ----------------
// 128x128 tile, BK=32, 4 waves (2x2), 4x4 16x16x32 frags per wave. m97 structure.
template <int OUTBF>
__global__ __launch_bounds__(256) void gemm_bt(const u16* __restrict__ A,
                                               const u16* __restrict__ B,
                                               void* __restrict__ C, int M, int N,
                                               int K) {
  __shared__ u16 lds[2][128 * 32];
  const int tid = threadIdx.x, l = tid & 63, w = tid >> 6;
  const int m0 = blockIdx.x * 128, n0 = blockIdx.y * 128;
  const int wr = w >> 1, wc = w & 1;
  f32x4 acc[4][4] = {};
  for (int k0 = 0; k0 < K; k0 += 32) {
#pragma unroll
    for (int i = 0; i < 2; ++i) {
      const int c = i * 256 + tid;
      const int row = c >> 2;
      const int scb = ((c & 3) << 4) ^ ((row & 3) << 4);
      gload16((const char*)A + ((size_t)(m0 + row) * K + k0) * 2 + scb,
              (char*)&lds[0][0] + (size_t)(i * 256 + w * 64) * 16);
      gload16((const char*)B + ((size_t)(n0 + row) * K + k0) * 2 + scb,
              (char*)&lds[1][0] + (size_t)(i * 256 + w * 64) * 16);
    }
    __syncthreads();
    bf16x8 af[4], bf[4];
#pragma unroll
    for (int f = 0; f < 4; ++f) {
      const int ra = wr * 64 + f * 16 + (l & 15);
      af[f] = *(const bf16x8*)((const char*)&lds[0][0] + ra * 64 +
                               (((l >> 4) * 16) ^ ((ra & 3) << 4)));
      const int rb = wc * 64 + f * 16 + (l & 15);
      bf[f] = *(const bf16x8*)((const char*)&lds[1][0] + rb * 64 +
                               (((l >> 4) * 16) ^ ((rb & 3) << 4)));
    }
#pragma unroll
    for (int mf = 0; mf < 4; ++mf)
#pragma unroll
      for (int nf = 0; nf < 4; ++nf)
        acc[mf][nf] = __builtin_amdgcn_mfma_f32_16x16x32_bf16(af[mf], bf[nf],
                                                              acc[mf][nf], 0, 0, 0);
    __syncthreads();
  }
#pragma unroll
  for (int mf = 0; mf < 4; ++mf) {
    const int rbase = m0 + wr * 64 + mf * 16 + ((l >> 4) << 2);
#pragma unroll
    for (int nf = 0; nf < 4; ++nf) {
      const int cc = n0 + wc * 64 + nf * 16 + (l & 15);
#pragma unroll
      for (int j = 0; j < 4; ++j) {
        if (OUTBF)
          ((u16*)C)[(size_t)(rbase + j) * N + cc] = f2bf(acc[mf][nf][j]);
        else
          ((float*)C)[(size_t)(rbase + j) * N + cc] = acc[mf][nf][j];
      }
    }
  }
}

// ---- Linformer projection as pure BT GEMM: hsEF[b][m][n] = sum_k EFt[m][k]*hsT2[b][n][k] ----
// 64x128 tile, BK=32, 4 waves (2x2), each wave 32x64 = 2x4 frags. grid (8,8,4)=256 blocks.
__global__ __launch_bounds__(256) void proj64(const u16* __restrict__ EFt,
                                              const u16* __restrict__ hsT2,
                                              u16* __restrict__ hsEF) {
  __shared__ u16 lA[64 * 32], lB[128 * 32];
  const int tid = threadIdx.x, l = tid & 63, w = tid >> 6;
  const int m0 = blockIdx.x * 64, n0 = blockIdx.y * 128, b = blockIdx.z;
  const u16* Bp = hsT2 + (size_t)b * 1024 * 4096;
  const int wr = w >> 1, wc = w & 1;
  f32x4 acc[2][4] = {};
  for (int k0 = 0; k0 < 4096; k0 += 32) {
    {  // A: 64 rows x 64B = 256 x 16B chunks (1 per thread)
      const int row = tid >> 2;
      const int scb = ((tid & 3) << 4) ^ ((row & 3) << 4);
      gload16((const char*)EFt + ((size_t)(m0 + row) * 4096 + k0) * 2 + scb,
              (char*)lA + (size_t)w * 64 * 16);
    }
#pragma unroll
    for (int i = 0; i < 2; ++i) {  // B: 128 rows x 64B = 512 chunks
      const int c = i * 256 + tid;
      const int row = c >> 2;
      const int scb = ((c & 3) << 4) ^ ((row & 3) << 4);
      gload16((const char*)Bp + ((size_t)(n0 + row) * 4096 + k0) * 2 + scb,
              (char*)lB + (size_t)(i * 256 + w * 64) * 16);
    }
    __syncthreads();
    bf16x8 af[2], bf[4];
#pragma unroll
    for (int f = 0; f < 2; ++f) {
      const int ra = wr * 32 + f * 16 + (l & 15);
      af[f] = *(const bf16x8*)((const char*)lA + ra * 64 +
                               (((l >> 4) * 16) ^ ((ra & 3) << 4)));
    }
#pragma unroll
    for (int f = 0; f < 4; ++f) {
      const int rb = wc * 64 + f * 16 + (l & 15);
      bf[f] = *(const bf16x8*)((const char*)lB + rb * 64 +
                               (((l >> 4) * 16) ^ ((rb & 3) << 4)));
    }
#pragma unroll
    for (int mf = 0; mf < 2; ++mf)
#pragma unroll
      for (int nf = 0; nf < 4; ++nf)
        acc[mf][nf] = __builtin_amdgcn_mfma_f32_16x16x32_bf16(af[mf], bf[nf],
                                                              acc[mf][nf], 0, 0, 0);
    __syncthreads();
  }
#pragma unroll
  for (int mf = 0; mf < 2; ++mf) {
    const int rbase = m0 + wr * 32 + mf * 16 + ((l >> 4) << 2);
#pragma unroll
    for (int nf = 0; nf < 4; ++nf) {
      const int cc = n0 + wc * 64 + nf * 16 + (l & 15);
#pragma unroll
      for (int j = 0; j < 4; ++j)
        hsEF[((size_t)b * 512 + rbase + j) * 1024 + cc] = f2bf(acc[mf][nf][j]);
    }
  }
}

// ---- combined K'/V' weight application: A = hsEF flat [2048][1024], B = Wk or Wv ----
// rows m0..m0+64 all within one (b, E/F) half. 64x128 tile. grid (32,8)=256 blocks.
__global__ __launch_bounds__(256) void gemm_kv(const u16* __restrict__ hsEF,
                                               const u16* __restrict__ Wk,
                                               const u16* __restrict__ Wv,
                                               u16* __restrict__ kproj,
                                               u16* __restrict__ vprojT) {
  __shared__ u16 lA[64 * 32], lB[128 * 32];
  const int tid = threadIdx.x, l = tid & 63, w = tid >> 6;
  const int m0 = blockIdx.x * 64, n0 = blockIdx.y * 128;
  const int b = m0 >> 9, half = (m0 >> 8) & 1;
  const u16* Bp = half ? Wv : Wk;
  const int wr = w >> 1, wc = w & 1;
  f32x4 acc[2][4] = {};
  for (int k0 = 0; k0 < 1024; k0 += 32) {
    {
      const int row = tid >> 2;
      const int scb = ((tid & 3) << 4) ^ ((row & 3) << 4);
      gload16((const char*)hsEF + ((size_t)(m0 + row) * 1024 + k0) * 2 + scb,
              (char*)lA + (size_t)w * 64 * 16);
    }
#pragma unroll
    for (int i = 0; i < 2; ++i) {
      const int c = i * 256 + tid;
      const int row = c >> 2;
      const int scb = ((c & 3) << 4) ^ ((row & 3) << 4);
      gload16((const char*)Bp + ((size_t)(n0 + row) * 1024 + k0) * 2 + scb,
              (char*)lB + (size_t)(i * 256 + w * 64) * 16);
    }
    __syncthreads();
    bf16x8 af[2], bf[4];
#pragma unroll
    for (int f = 0; f < 2; ++f) {
      const int ra = wr * 32 + f * 16 + (l & 15);
      af[f] = *(const bf16x8*)((const char*)lA + ra * 64 +
                               (((l >> 4) * 16) ^ ((ra & 3) << 4)));
    }
#pragma unroll
    for (int f = 0; f < 4; ++f) {
      const int rb = wc * 64 + f * 16 + (l & 15);
      bf[f] = *(const bf16x8*)((const char*)lB + rb * 64 +
                               (((l >> 4) * 16) ^ ((rb & 3) << 4)));
    }
#pragma unroll
    for (int mf = 0; mf < 2; ++mf)
#pragma unroll
      for (int nf = 0; nf < 4; ++nf)
        acc[mf][nf] = __builtin_amdgcn_mfma_f32_16x16x32_bf16(af[mf], bf[nf],
                                                              acc[mf][nf], 0, 0, 0);
    __syncthreads();
  }
#pragma unroll
  for (int mf = 0; mf < 2; ++mf) {
    const int kp0 = (m0 & 255) + wr * 32 + mf * 16 + ((l >> 4) << 2);
#pragma unroll
    for (int nf = 0; nf < 4; ++nf) {
      const int n = n0 + wc * 64 + nf * 16 + (l & 15);
      if (!half) {
#pragma unroll
        for (int j = 0; j < 4; ++j)
          kproj[((size_t)b * 256 + kp0 + j) * 1024 + n] = f2bf(acc[mf][nf][j]);
      } else {
        u16x4 o = {f2bf(acc[mf][nf][0]), f2bf(acc[mf][nf][1]), f2bf(acc[mf][nf][2]),
                   f2bf(acc[mf][nf][3])};
        *(u16x4*)(vprojT + ((size_t)b * 1024 + n) * 256 + kp0) = o;
      }
    }
  }
}

// ---------------- fused attention (unchanged from passing R2) ----------------
__global__ __launch_bounds__(256) void attn_kernel(const u16* __restrict__ qmat,
                                                   const u16* __restrict__ kproj,
                                                   const u16* __restrict__ vprojT,
                                                   u16* __restrict__ aout) {
  __shared__ u16 smem[32768];
  const int tid = threadIdx.x, l = tid & 63, w = tid >> 6;
  const int qt = blockIdx.x, h = blockIdx.y, b = blockIdx.z;
  const int qbase = qt * 64;

#pragma unroll
  for (int i = 0; i < 8; ++i) {  // K' [256][128B], swz (row&7)<<4
    const int c = i * 256 + tid;
    const int row = c >> 3;
    const int scb = ((c & 7) << 4) ^ ((row & 7) << 4);
    gload16((const char*)kproj + (((size_t)(b * 256 + row)) * 1024 + h * 64) * 2 + scb,
            (char*)smem + (size_t)(i * 256 + w * 64) * 16);
  }
#pragma unroll
  for (int i = 0; i < 8; ++i) {  // V'^T [64][512B], swz (d&31)<<4
    const int c = i * 256 + tid;
    const int d = c >> 5;
    const int scb = ((c & 31) << 4) ^ ((d & 31) << 4);
    gload16((const char*)vprojT + ((size_t)(b * 1024 + h * 64 + d)) * 256 * 2 + scb,
            (char*)smem + 32768 + (size_t)(i * 256 + w * 64) * 16);
  }
  __syncthreads();

  const u16* qrow =
      qmat + ((size_t)(b * 4096 + qbase + w * 16 + (l & 15))) * 1024 + h * 64;
  bf16x8 qa[2];
#pragma unroll
  for (int kf = 0; kf < 2; ++kf)
    qa[kf] = *(const bf16x8*)(qrow + kf * 32 + (l >> 4) * 8);

  f32x4 s[16] = {};
#pragma unroll
  for (int nf = 0; nf < 16; ++nf) {
    const int kr = nf * 16 + (l & 15);
#pragma unroll
    for (int kf = 0; kf < 2; ++kf) {
      const bf16x8 kb = *(const bf16x8*)((const char*)smem + kr * 128 +
                                         ((kf * 64 + (l >> 4) * 16) ^ ((kr & 7) << 4)));
      s[nf] = __builtin_amdgcn_mfma_f32_16x16x32_bf16(qa[kf], kb, s[nf], 0, 0, 0);
    }
  }

  float mx[4] = {-1e30f, -1e30f, -1e30f, -1e30f}, sum[4] = {0.f, 0.f, 0.f, 0.f};
#pragma unroll
  for (int j = 0; j < 4; ++j) {
#pragma unroll
    for (int nf = 0; nf < 16; ++nf) mx[j] = fmaxf(mx[j], s[nf][j]);
#pragma unroll
    for (int m = 1; m < 16; m <<= 1) mx[j] = fmaxf(mx[j], __shfl_xor(mx[j], m, 64));
  }
#pragma unroll
  for (int nf = 0; nf < 16; ++nf)
#pragma unroll
    for (int j = 0; j < 4; ++j) {
      const float e = __expf((s[nf][j] - mx[j]) * 0.125f);
      s[nf][j] = e;
      sum[j] += e;
    }
#pragma unroll
  for (int j = 0; j < 4; ++j) {
#pragma unroll
    for (int m = 1; m < 16; m <<= 1) sum[j] += __shfl_xor(sum[j], m, 64);
    sum[j] = 1.0f / sum[j];
  }

  __syncthreads();

  u16* Pw = smem + w * 4096;
#pragma unroll
  for (int nf = 0; nf < 16; ++nf) {
    const int col = nf * 16 + (l & 15);
#pragma unroll
    for (int j = 0; j < 4; ++j) {
      const int row = (l >> 4) * 4 + j;
      *(u16*)((char*)Pw + row * 512 + ((col * 2) ^ (row << 4))) =
          f2bf(s[nf][j] * sum[j]);
    }
  }
  __syncthreads();

  f32x4 o[4] = {};
#pragma unroll
  for (int kf = 0; kf < 8; ++kf) {
    const int q = l & 15;
    const bf16x8 pb = *(const bf16x8*)((const char*)Pw + q * 512 +
                                       ((kf * 64 + (l >> 4) * 16) ^ (q << 4)));
#pragma unroll
    for (int mf = 0; mf < 4; ++mf) {
      const int d = mf * 16 + (l & 15);
      const bf16x8 va = *(const bf16x8*)((const char*)smem + 32768 + d * 512 +
                                         ((kf * 64 + (l >> 4) * 16) ^ ((d & 31) << 4)));
      o[mf] = __builtin_amdgcn_mfma_f32_16x16x32_bf16(va, pb, o[mf], 0, 0, 0);
    }
  }

#pragma unroll
  for (int mf = 0; mf < 4; ++mf) {
    const int d0 = mf * 16 + ((l >> 4) << 2);
    const int srow = b * 4096 + qbase + w * 16 + (l & 15);
    u16x4 ov = {f2bf(o[mf][0]), f2bf(o[mf][1]), f2bf(o[mf][2]), f2bf(o[mf][3])};
    *(u16x4*)(aout + (size_t)srow * 1024 + h * 64 + d0) = ov;
  }
}

// ---------------- host launch ----------------
extern "C" void kernel_launch(void* const* d_in, const int* in_sizes, int n_in,
                              void* d_out, int out_size, void* d_ws, size_t ws_size,
                              hipStream_t stream) {
  const float* hs = (const float*)d_in[0];
  const float* Wq = (const float*)d_in[1];
  const float* Wk = (const float*)d_in[2];
  const float* Wv = (const float*)d_in[3];
  const float* Wo = (const float*)d_in[4];
  const float* E = (const float*)d_in[5];
  const float* F = (const float*)d_in[6];

  // Workspace layout: peak 116 MiB (same footprint that passed in R2).
  // aout ALIASES hsT2: hsT2 is dead after proj64; aout is first written by
  // attn_kernel which runs strictly later on the same stream.
  char* ws = (char*)d_ws;
  u16* hs_bf = (u16*)(ws + 0);              // 32 MiB [16384][1024]
  u16* hsT2 = (u16*)(ws + 33554432);        // 32 MiB [4][1024][4096]
  u16* aout = hsT2;                         // 32 MiB [16384][1024] (alias)
  u16* qout = (u16*)(ws + 67108864);        // 32 MiB [16384][1024]
  u16* Wall = (u16*)(ws + 100663296);       // 8 MiB  Wq|Wk|Wv|Wo bf16
  u16* EFt = (u16*)(ws + 109051904);        // 4 MiB  [512][4096]
  u16* hsEF = (u16*)(ws + 113246208);       // 4 MiB  [4][512][1024]
  u16* kproj = (u16*)(ws + 117440512);      // 2 MiB  [4][256][1024]
  u16* vprojT = (u16*)(ws + 119537664);     // 2 MiB  [4][1024][256]
  // peak = 121634816 bytes ~= 116 MiB

  conv_hs<<<dim3(512, 32), 256, 0, stream>>>(hs, hs_bf, hsT2);
  conv_w4<<<dim3(1024, 4), 256, 0, stream>>>(Wq, Wk, Wv, Wo, Wall);
  transpose_conv<<<dim3(128, 8), 256, 0, stream>>>(E, EFt);
  transpose_conv<<<dim3(128, 8), 256, 0, stream>>>(F, EFt + (size_t)256 * 4096);

  // q = hs @ Wq^T
  gemm_bt<1><<<dim3(128, 8), 256, 0, stream>>>(hs_bf, Wall, qout, 16384, 1024, 1024);
  // hsEF[b] = [E;F]^T @ hs[b]
  proj64<<<dim3(8, 8, 4), 256, 0, stream>>>(EFt, hsT2, hsEF);
  // kproj = hsE @ Wk^T ; vprojT = (hsF @ Wv^T)^T
  gemm_kv<<<dim3(32, 8), 256, 0, stream>>>(hsEF, Wall + 1048576, Wall + 2097152,
                                           kproj, vprojT);
  // attn writes aout (reuses hsT2's space; hsT2 consumed by proj64 above)
  attn_kernel<<<dim3(64, 16, 4), 256, 0, stream>>>(qout, kproj, vprojT, aout);
  // out = attn_out @ Wo^T (fp32 epilogue)
  gemm_bt<0><<<dim3(128, 8), 256, 0, stream>>>(aout, Wall + 3145728, d_out, 16384,
                                               1024, 1024);
}

// Round 11
// 369.524 us; speedup vs baseline: 1.2593x; 1.0935x over previous
//
#include <hip/hip_runtime.h>

typedef unsigned short u16;
typedef unsigned int u32;
typedef __attribute__((ext_vector_type(8))) __bf16 bf16x8;
typedef __attribute__((ext_vector_type(4))) float f32x4;
typedef __attribute__((ext_vector_type(8))) u16 u16x8;
typedef __attribute__((ext_vector_type(4))) u16 u16x4;

typedef const __attribute__((address_space(1))) u32* gas_p;
typedef __attribute__((address_space(3))) u32* las_p;

__device__ __forceinline__ void gload16(const void* g, void* l) {
  __builtin_amdgcn_global_load_lds((gas_p)g, (las_p)l, 16, 0, 0);
}

__device__ __forceinline__ u16 f2bf(float f) {
  u32 u = __builtin_bit_cast(u32, f);
  u32 r = (u + 0x7fffu + ((u >> 16) & 1u)) >> 16;
  return (u16)r;
}

// ---- fused hs conversion: hs [16384][1024] f32 -> hs_bf (same layout) + hsT2 [4][1024][4096] ----
__global__ __launch_bounds__(256) void conv_hs(const float* __restrict__ in,
                                               u16* __restrict__ out_row,
                                               u16* __restrict__ out_t) {
  __shared__ u16 t[32][34];
  const int r0 = blockIdx.x * 32, c0 = blockIdx.y * 32;
  const int lx = threadIdx.x & 31, ly = threadIdx.x >> 5;  // ly: 0..7
#pragma unroll
  for (int i = 0; i < 4; ++i) {
    const int r = r0 + ly + i * 8;
    const u16 v = f2bf(in[(size_t)r * 1024 + c0 + lx]);
    out_row[(size_t)r * 1024 + c0 + lx] = v;
    t[ly + i * 8][lx] = v;
  }
  __syncthreads();
  const int b = r0 >> 12, s0 = r0 & 4095;
#pragma unroll
  for (int i = 0; i < 4; ++i)
    out_t[((size_t)b * 1024 + c0 + ly + i * 8) * 4096 + s0 + lx] = t[lx][ly + i * 8];
}

// ---- 4 weight matrices fp32 -> bf16, one launch ----
__global__ __launch_bounds__(256) void conv_w4(const float* __restrict__ a,
                                               const float* __restrict__ b,
                                               const float* __restrict__ c,
                                               const float* __restrict__ d,
                                               u16* __restrict__ out) {
  const float* src = blockIdx.y == 0 ? a : blockIdx.y == 1 ? b : blockIdx.y == 2 ? c : d;
  const int i = (blockIdx.x * 256 + threadIdx.x) * 4;
  const float4 v = *(const float4*)(src + i);
  u16x4 o = {f2bf(v.x), f2bf(v.y), f2bf(v.z), f2bf(v.w)};
  *(u16x4*)(out + (size_t)blockIdx.y * 1048576 + i) = o;
}

// ---- transpose + convert: in [4096][256] f32 -> out [256][4096] bf16 ----
__global__ __launch_bounds__(256) void transpose_conv(const float* __restrict__ in,
                                                      u16* __restrict__ out) {
  const int R = 4096, Cc = 256;
  __shared__ float t[32][33];
  const int r0 = blockIdx.x * 32, c0 = blockIdx.y * 32;
  const int lx = threadIdx.x & 31, ly = threadIdx.x >> 5;
#pragma unroll
  for (int i = 0; i < 4; ++i)
    t[ly + i * 8][lx] = in[(size_t)(r0 + ly + i * 8) * Cc + c0 + lx];
  __syncthreads();
#pragma unroll
  for (int i = 0; i < 4; ++i)
    out[(size_t)(c0 + ly + i * 8) * R + r0 + lx] = f2bf(t[lx][ly + i * 8]);
}

// ---------------- bf16 GEMM: C[M][N] = A[M][K] * B[N][K]^T ----------------
// 128x128 tile, BK=64, 4 waves (2x2), 4x4 frags, 32 MFMA/wave per barrier pair.
// LDS rows are 128B; swizzle byte ^= (row&7)<<4 (pattern proven in attn K'-staging).
template <int OUTBF>
__global__ __launch_bounds__(256) void gemm_bt(const u16* __restrict__ A,
                                               const u16* __restrict__ B,
                                               void* __restrict__ C, int M, int N,
                                               int K) {
  __shared__ u16 lds[2][128 * 64];  // 32 KiB total
  const int tid = threadIdx.x, l = tid & 63, w = tid >> 6;
  const int m0 = blockIdx.x * 128, n0 = blockIdx.y * 128;
  const int wr = w >> 1, wc = w & 1;
  f32x4 acc[4][4] = {};
  for (int k0 = 0; k0 < K; k0 += 64) {
#pragma unroll
    for (int i = 0; i < 4; ++i) {
      const int c = i * 256 + tid;
      const int row = c >> 3;
      const int scb = ((c & 7) << 4) ^ ((row & 7) << 4);
      gload16((const char*)A + ((size_t)(m0 + row) * K + k0) * 2 + scb,
              (char*)&lds[0][0] + (size_t)(i * 256 + w * 64) * 16);
      gload16((const char*)B + ((size_t)(n0 + row) * K + k0) * 2 + scb,
              (char*)&lds[1][0] + (size_t)(i * 256 + w * 64) * 16);
    }
    __syncthreads();
#pragma unroll
    for (int kk = 0; kk < 2; ++kk) {
      bf16x8 af[4], bf[4];
#pragma unroll
      for (int f = 0; f < 4; ++f) {
        const int ra = wr * 64 + f * 16 + (l & 15);
        af[f] = *(const bf16x8*)((const char*)&lds[0][0] + ra * 128 +
                                 (((l >> 4) * 16 + kk * 64) ^ ((ra & 7) << 4)));
        const int rb = wc * 64 + f * 16 + (l & 15);
        bf[f] = *(const bf16x8*)((const char*)&lds[1][0] + rb * 128 +
                                 (((l >> 4) * 16 + kk * 64) ^ ((rb & 7) << 4)));
      }
#pragma unroll
      for (int mf = 0; mf < 4; ++mf)
#pragma unroll
        for (int nf = 0; nf < 4; ++nf)
          acc[mf][nf] = __builtin_amdgcn_mfma_f32_16x16x32_bf16(af[mf], bf[nf],
                                                                acc[mf][nf], 0, 0, 0);
    }
    __syncthreads();
  }
#pragma unroll
  for (int mf = 0; mf < 4; ++mf) {
    const int rbase = m0 + wr * 64 + mf * 16 + ((l >> 4) << 2);
#pragma unroll
    for (int nf = 0; nf < 4; ++nf) {
      const int cc = n0 + wc * 64 + nf * 16 + (l & 15);
#pragma unroll
      for (int j = 0; j < 4; ++j) {
        if (OUTBF)
          ((u16*)C)[(size_t)(rbase + j) * N + cc] = f2bf(acc[mf][nf][j]);
        else
          ((float*)C)[(size_t)(rbase + j) * N + cc] = acc[mf][nf][j];
      }
    }
  }
}

// ---- Linformer projection as pure BT GEMM: hsEF[b][m][n] = sum_k EFt[m][k]*hsT2[b][n][k] ----
// 64x128 tile, BK=64, 4 waves (2x2), 2x4 frags, 16 MFMA/wave per barrier pair.
__global__ __launch_bounds__(256) void proj64(const u16* __restrict__ EFt,
                                              const u16* __restrict__ hsT2,
                                              u16* __restrict__ hsEF) {
  __shared__ u16 lA[64 * 64], lB[128 * 64];  // 8 KiB + 16 KiB
  const int tid = threadIdx.x, l = tid & 63, w = tid >> 6;
  const int m0 = blockIdx.x * 64, n0 = blockIdx.y * 128, b = blockIdx.z;
  const u16* Bp = hsT2 + (size_t)b * 1024 * 4096;
  const int wr = w >> 1, wc = w & 1;
  f32x4 acc[2][4] = {};
  for (int k0 = 0; k0 < 4096; k0 += 64) {
#pragma unroll
    for (int i = 0; i < 2; ++i) {  // A: 64 rows x 128B = 512 chunks
      const int c = i * 256 + tid;
      const int row = c >> 3;
      const int scb = ((c & 7) << 4) ^ ((row & 7) << 4);
      gload16((const char*)EFt + ((size_t)(m0 + row) * 4096 + k0) * 2 + scb,
              (char*)lA + (size_t)(i * 256 + w * 64) * 16);
    }
#pragma unroll
    for (int i = 0; i < 4; ++i) {  // B: 128 rows x 128B = 1024 chunks
      const int c = i * 256 + tid;
      const int row = c >> 3;
      const int scb = ((c & 7) << 4) ^ ((row & 7) << 4);
      gload16((const char*)Bp + ((size_t)(n0 + row) * 4096 + k0) * 2 + scb,
              (char*)lB + (size_t)(i * 256 + w * 64) * 16);
    }
    __syncthreads();
#pragma unroll
    for (int kk = 0; kk < 2; ++kk) {
      bf16x8 af[2], bf[4];
#pragma unroll
      for (int f = 0; f < 2; ++f) {
        const int ra = wr * 32 + f * 16 + (l & 15);
        af[f] = *(const bf16x8*)((const char*)lA + ra * 128 +
                                 (((l >> 4) * 16 + kk * 64) ^ ((ra & 7) << 4)));
      }
#pragma unroll
      for (int f = 0; f < 4; ++f) {
        const int rb = wc * 64 + f * 16 + (l & 15);
        bf[f] = *(const bf16x8*)((const char*)lB + rb * 128 +
                                 (((l >> 4) * 16 + kk * 64) ^ ((rb & 7) << 4)));
      }
#pragma unroll
      for (int mf = 0; mf < 2; ++mf)
#pragma unroll
        for (int nf = 0; nf < 4; ++nf)
          acc[mf][nf] = __builtin_amdgcn_mfma_f32_16x16x32_bf16(af[mf], bf[nf],
                                                                acc[mf][nf], 0, 0, 0);
    }
    __syncthreads();
  }
#pragma unroll
  for (int mf = 0; mf < 2; ++mf) {
    const int rbase = m0 + wr * 32 + mf * 16 + ((l >> 4) << 2);
#pragma unroll
    for (int nf = 0; nf < 4; ++nf) {
      const int cc = n0 + wc * 64 + nf * 16 + (l & 15);
#pragma unroll
      for (int j = 0; j < 4; ++j)
        hsEF[((size_t)b * 512 + rbase + j) * 1024 + cc] = f2bf(acc[mf][nf][j]);
    }
  }
}

// ---- combined K'/V' weight application: A = hsEF flat [2048][1024], B = Wk or Wv ----
// 64x128 tile, BK=64. grid (32,8)=256 blocks.
__global__ __launch_bounds__(256) void gemm_kv(const u16* __restrict__ hsEF,
                                               const u16* __restrict__ Wk,
                                               const u16* __restrict__ Wv,
                                               u16* __restrict__ kproj,
                                               u16* __restrict__ vprojT) {
  __shared__ u16 lA[64 * 64], lB[128 * 64];
  const int tid = threadIdx.x, l = tid & 63, w = tid >> 6;
  const int m0 = blockIdx.x * 64, n0 = blockIdx.y * 128;
  const int b = m0 >> 9, half = (m0 >> 8) & 1;
  const u16* Bp = half ? Wv : Wk;
  const int wr = w >> 1, wc = w & 1;
  f32x4 acc[2][4] = {};
  for (int k0 = 0; k0 < 1024; k0 += 64) {
#pragma unroll
    for (int i = 0; i < 2; ++i) {
      const int c = i * 256 + tid;
      const int row = c >> 3;
      const int scb = ((c & 7) << 4) ^ ((row & 7) << 4);
      gload16((const char*)hsEF + ((size_t)(m0 + row) * 1024 + k0) * 2 + scb,
              (char*)lA + (size_t)(i * 256 + w * 64) * 16);
    }
#pragma unroll
    for (int i = 0; i < 4; ++i) {
      const int c = i * 256 + tid;
      const int row = c >> 3;
      const int scb = ((c & 7) << 4) ^ ((row & 7) << 4);
      gload16((const char*)Bp + ((size_t)(n0 + row) * 1024 + k0) * 2 + scb,
              (char*)lB + (size_t)(i * 256 + w * 64) * 16);
    }
    __syncthreads();
#pragma unroll
    for (int kk = 0; kk < 2; ++kk) {
      bf16x8 af[2], bf[4];
#pragma unroll
      for (int f = 0; f < 2; ++f) {
        const int ra = wr * 32 + f * 16 + (l & 15);
        af[f] = *(const bf16x8*)((const char*)lA + ra * 128 +
                                 (((l >> 4) * 16 + kk * 64) ^ ((ra & 7) << 4)));
      }
#pragma unroll
      for (int f = 0; f < 4; ++f) {
        const int rb = wc * 64 + f * 16 + (l & 15);
        bf[f] = *(const bf16x8*)((const char*)lB + rb * 128 +
                                 (((l >> 4) * 16 + kk * 64) ^ ((rb & 7) << 4)));
      }
#pragma unroll
      for (int mf = 0; mf < 2; ++mf)
#pragma unroll
        for (int nf = 0; nf < 4; ++nf)
          acc[mf][nf] = __builtin_amdgcn_mfma_f32_16x16x32_bf16(af[mf], bf[nf],
                                                                acc[mf][nf], 0, 0, 0);
    }
    __syncthreads();
  }
#pragma unroll
  for (int mf = 0; mf < 2; ++mf) {
    const int kp0 = (m0 & 255) + wr * 32 + mf * 16 + ((l >> 4) << 2);
#pragma unroll
    for (int nf = 0; nf < 4; ++nf) {
      const int n = n0 + wc * 64 + nf * 16 + (l & 15);
      if (!half) {
#pragma unroll
        for (int j = 0; j < 4; ++j)
          kproj[((size_t)b * 256 + kp0 + j) * 1024 + n] = f2bf(acc[mf][nf][j]);
      } else {
        u16x4 o = {f2bf(acc[mf][nf][0]), f2bf(acc[mf][nf][1]), f2bf(acc[mf][nf][2]),
                   f2bf(acc[mf][nf][3])};
        *(u16x4*)(vprojT + ((size_t)b * 1024 + n) * 256 + kp0) = o;
      }
    }
  }
}

// ---------------- fused attention (unchanged from passing R7) ----------------
__global__ __launch_bounds__(256) void attn_kernel(const u16* __restrict__ qmat,
                                                   const u16* __restrict__ kproj,
                                                   const u16* __restrict__ vprojT,
                                                   u16* __restrict__ aout) {
  __shared__ u16 smem[32768];
  const int tid = threadIdx.x, l = tid & 63, w = tid >> 6;
  const int qt = blockIdx.x, h = blockIdx.y, b = blockIdx.z;
  const int qbase = qt * 64;

#pragma unroll
  for (int i = 0; i < 8; ++i) {  // K' [256][128B], swz (row&7)<<4
    const int c = i * 256 + tid;
    const int row = c >> 3;
    const int scb = ((c & 7) << 4) ^ ((row & 7) << 4);
    gload16((const char*)kproj + (((size_t)(b * 256 + row)) * 1024 + h * 64) * 2 + scb,
            (char*)smem + (size_t)(i * 256 + w * 64) * 16);
  }
#pragma unroll
  for (int i = 0; i < 8; ++i) {  // V'^T [64][512B], swz (d&31)<<4
    const int c = i * 256 + tid;
    const int d = c >> 5;
    const int scb = ((c & 31) << 4) ^ ((d & 31) << 4);
    gload16((const char*)vprojT + ((size_t)(b * 1024 + h * 64 + d)) * 256 * 2 + scb,
            (char*)smem + 32768 + (size_t)(i * 256 + w * 64) * 16);
  }
  __syncthreads();

  const u16* qrow =
      qmat + ((size_t)(b * 4096 + qbase + w * 16 + (l & 15))) * 1024 + h * 64;
  bf16x8 qa[2];
#pragma unroll
  for (int kf = 0; kf < 2; ++kf)
    qa[kf] = *(const bf16x8*)(qrow + kf * 32 + (l >> 4) * 8);

  f32x4 s[16] = {};
#pragma unroll
  for (int nf = 0; nf < 16; ++nf) {
    const int kr = nf * 16 + (l & 15);
#pragma unroll
    for (int kf = 0; kf < 2; ++kf) {
      const bf16x8 kb = *(const bf16x8*)((const char*)smem + kr * 128 +
                                         ((kf * 64 + (l >> 4) * 16) ^ ((kr & 7) << 4)));
      s[nf] = __builtin_amdgcn_mfma_f32_16x16x32_bf16(qa[kf], kb, s[nf], 0, 0, 0);
    }
  }

  float mx[4] = {-1e30f, -1e30f, -1e30f, -1e30f}, sum[4] = {0.f, 0.f, 0.f, 0.f};
#pragma unroll
  for (int j = 0; j < 4; ++j) {
#pragma unroll
    for (int nf = 0; nf < 16; ++nf) mx[j] = fmaxf(mx[j], s[nf][j]);
#pragma unroll
    for (int m = 1; m < 16; m <<= 1) mx[j] = fmaxf(mx[j], __shfl_xor(mx[j], m, 64));
  }
#pragma unroll
  for (int nf = 0; nf < 16; ++nf)
#pragma unroll
    for (int j = 0; j < 4; ++j) {
      const float e = __expf((s[nf][j] - mx[j]) * 0.125f);
      s[nf][j] = e;
      sum[j] += e;
    }
#pragma unroll
  for (int j = 0; j < 4; ++j) {
#pragma unroll
    for (int m = 1; m < 16; m <<= 1) sum[j] += __shfl_xor(sum[j], m, 64);
    sum[j] = 1.0f / sum[j];
  }

  __syncthreads();

  u16* Pw = smem + w * 4096;
#pragma unroll
  for (int nf = 0; nf < 16; ++nf) {
    const int col = nf * 16 + (l & 15);
#pragma unroll
    for (int j = 0; j < 4; ++j) {
      const int row = (l >> 4) * 4 + j;
      *(u16*)((char*)Pw + row * 512 + ((col * 2) ^ (row << 4))) =
          f2bf(s[nf][j] * sum[j]);
    }
  }
  __syncthreads();

  f32x4 o[4] = {};
#pragma unroll
  for (int kf = 0; kf < 8; ++kf) {
    const int q = l & 15;
    const bf16x8 pb = *(const bf16x8*)((const char*)Pw + q * 512 +
                                       ((kf * 64 + (l >> 4) * 16) ^ (q << 4)));
#pragma unroll
    for (int mf = 0; mf < 4; ++mf) {
      const int d = mf * 16 + (l & 15);
      const bf16x8 va = *(const bf16x8*)((const char*)smem + 32768 + d * 512 +
                                         ((kf * 64 + (l >> 4) * 16) ^ ((d & 31) << 4)));
      o[mf] = __builtin_amdgcn_mfma_f32_16x16x32_bf16(va, pb, o[mf], 0, 0, 0);
    }
  }

#pragma unroll
  for (int mf = 0; mf < 4; ++mf) {
    const int d0 = mf * 16 + ((l >> 4) << 2);
    const int srow = b * 4096 + qbase + w * 16 + (l & 15);
    u16x4 ov = {f2bf(o[mf][0]), f2bf(o[mf][1]), f2bf(o[mf][2]), f2bf(o[mf][3])};
    *(u16x4*)(aout + (size_t)srow * 1024 + h * 64 + d0) = ov;
  }
}

// ---------------- host launch ----------------
extern "C" void kernel_launch(void* const* d_in, const int* in_sizes, int n_in,
                              void* d_out, int out_size, void* d_ws, size_t ws_size,
                              hipStream_t stream) {
  const float* hs = (const float*)d_in[0];
  const float* Wq = (const float*)d_in[1];
  const float* Wk = (const float*)d_in[2];
  const float* Wv = (const float*)d_in[3];
  const float* Wo = (const float*)d_in[4];
  const float* E = (const float*)d_in[5];
  const float* F = (const float*)d_in[6];

  // Workspace layout: peak 116 MiB (proven in R2/R7).
  // aout ALIASES hsT2: hsT2 dead after proj64; aout first written by attn_kernel.
  char* ws = (char*)d_ws;
  u16* hs_bf = (u16*)(ws + 0);              // 32 MiB [16384][1024]
  u16* hsT2 = (u16*)(ws + 33554432);        // 32 MiB [4][1024][4096]
  u16* aout = hsT2;                         // 32 MiB [16384][1024] (alias)
  u16* qout = (u16*)(ws + 67108864);        // 32 MiB [16384][1024]
  u16* Wall = (u16*)(ws + 100663296);       // 8 MiB  Wq|Wk|Wv|Wo bf16
  u16* EFt = (u16*)(ws + 109051904);        // 4 MiB  [512][4096]
  u16* hsEF = (u16*)(ws + 113246208);       // 4 MiB  [4][512][1024]
  u16* kproj = (u16*)(ws + 117440512);      // 2 MiB  [4][256][1024]
  u16* vprojT = (u16*)(ws + 119537664);     // 2 MiB  [4][1024][256]

  conv_hs<<<dim3(512, 32), 256, 0, stream>>>(hs, hs_bf, hsT2);
  conv_w4<<<dim3(1024, 4), 256, 0, stream>>>(Wq, Wk, Wv, Wo, Wall);
  transpose_conv<<<dim3(128, 8), 256, 0, stream>>>(E, EFt);
  transpose_conv<<<dim3(128, 8), 256, 0, stream>>>(F, EFt + (size_t)256 * 4096);

  // q = hs @ Wq^T
  gemm_bt<1><<<dim3(128, 8), 256, 0, stream>>>(hs_bf, Wall, qout, 16384, 1024, 1024);
  // hsEF[b] = [E;F]^T @ hs[b]
  proj64<<<dim3(8, 8, 4), 256, 0, stream>>>(EFt, hsT2, hsEF);
  // kproj = hsE @ Wk^T ; vprojT = (hsF @ Wv^T)^T
  gemm_kv<<<dim3(32, 8), 256, 0, stream>>>(hsEF, Wall + 1048576, Wall + 2097152,
                                           kproj, vprojT);
  attn_kernel<<<dim3(64, 16, 4), 256, 0, stream>>>(qout, kproj, vprojT, aout);
  // out = attn_out @ Wo^T (fp32 epilogue)
  gemm_bt<0><<<dim3(128, 8), 256, 0, stream>>>(aout, Wall + 3145728, d_out, 16384,
                                               1024, 1024);
}